// Round 1
// baseline (473.802 us; speedup 1.0000x reference)
//
#include <hip/hip_runtime.h>
#include <stdint.h>

// Problem constants
#define BB 4
#define TT 2048
#define CC 1024
#define HH 16
#define DH 64   // head dim

typedef __bf16 bf16x8 __attribute__((ext_vector_type(8)));
typedef float f32x4 __attribute__((ext_vector_type(4)));
typedef unsigned short ushort8 __attribute__((ext_vector_type(8)));
typedef unsigned short ushort4v __attribute__((ext_vector_type(4)));

__device__ __forceinline__ unsigned short f2b(float f) {
    union { float f; unsigned u; } v; v.f = f;
    unsigned r = v.u + 0x7FFFu + ((v.u >> 16) & 1u);   // RNE
    return (unsigned short)(r >> 16);
}
__device__ __forceinline__ float b2f(unsigned short s) {
    union { unsigned u; float f; } v; v.u = ((unsigned)s) << 16;
    return v.f;
}

// ---------------- fp32 -> bf16 cast, 4 elems/thread ----------------
__global__ __launch_bounds__(256) void k_f32_to_bf16(const float* __restrict__ in,
                                                     unsigned short* __restrict__ out, int n) {
    int i = (blockIdx.x * 256 + threadIdx.x) * 4;
    if (i >= n) return;
    float4 v = *(const float4*)(in + i);
    ushort4v o;
    o.x = f2b(v.x); o.y = f2b(v.y); o.z = f2b(v.z); o.w = f2b(v.w);
    *(ushort4v*)(out + i) = o;
}

// ------------- transpose + cast: in fp32 [R][Cc] -> out bf16 [Cc][R] -------------
__global__ __launch_bounds__(256) void k_transpose_bf16(const float* __restrict__ in,
                                                        unsigned short* __restrict__ out,
                                                        int R, int Cc) {
    __shared__ float tile[32][33];   // +1 pad breaks bank conflicts
    int bx = blockIdx.x * 32, by = blockIdx.y * 32;
    int tx = threadIdx.x, ty = threadIdx.y;   // (32, 8)
    for (int i = 0; i < 32; i += 8)
        tile[ty + i][tx] = in[(size_t)(by + ty + i) * Cc + bx + tx];
    __syncthreads();
    for (int i = 0; i < 32; i += 8)
        out[(size_t)(bx + ty + i) * R + by + tx] = f2b(tile[tx][ty + i]);
}

// ------------- bf16 MFMA GEMM: C[M][N] = A[M][K] * Bt[N][K]^T + bias -------------
// 128x128 block tile, BK=32, 256 threads = 4 waves (2x2 of 64x64 wave tiles)
template <int OUTF32>
__global__ __launch_bounds__(256) void k_gemm_bt(const unsigned short* __restrict__ A,
                                                 const unsigned short* __restrict__ Bt,
                                                 const float* __restrict__ bias,
                                                 void* __restrict__ out,
                                                 int M, int N, int K) {
    __shared__ unsigned short As[128 * 32];
    __shared__ unsigned short Bs[128 * 32];
    const int t = threadIdx.x;
    const int lane = t & 63;
    const int c = lane & 15, qd = lane >> 4;
    const int wave = t >> 6;
    const int wr = (wave >> 1) * 64, wc = (wave & 1) * 64;
    const size_t bm = (size_t)blockIdx.x * 128, bn = (size_t)blockIdx.y * 128;
    const int srow = t >> 2, scol = (t & 3) * 8;   // staging: 64 rows x 4 chunks per 256 thr

    f32x4 acc[4][4];
    for (int i = 0; i < 4; i++)
        for (int j = 0; j < 4; j++)
            acc[i][j] = (f32x4){0.f, 0.f, 0.f, 0.f};

    const unsigned short* Ap = A + (bm + srow) * (size_t)K + scol;
    const unsigned short* Bp = Bt + (bn + srow) * (size_t)K + scol;

    for (int k0 = 0; k0 < K; k0 += 32) {
        ushort8 a0 = *(const ushort8*)(Ap + k0);
        ushort8 a1 = *(const ushort8*)(Ap + (size_t)64 * K + k0);
        ushort8 b0 = *(const ushort8*)(Bp + k0);
        ushort8 b1 = *(const ushort8*)(Bp + (size_t)64 * K + k0);
        __syncthreads();   // previous iter's LDS reads complete
        *(ushort8*)&As[srow * 32 + scol] = a0;
        *(ushort8*)&As[(64 + srow) * 32 + scol] = a1;
        *(ushort8*)&Bs[srow * 32 + scol] = b0;
        *(ushort8*)&Bs[(64 + srow) * 32 + scol] = b1;
        __syncthreads();
        bf16x8 afr[4], bfr[4];
        for (int i = 0; i < 4; i++)
            afr[i] = *(const bf16x8*)&As[(wr + i * 16 + c) * 32 + qd * 8];
        for (int j = 0; j < 4; j++)
            bfr[j] = *(const bf16x8*)&Bs[(wc + j * 16 + c) * 32 + qd * 8];
        for (int i = 0; i < 4; i++)
            for (int j = 0; j < 4; j++)
                acc[i][j] = __builtin_amdgcn_mfma_f32_16x16x32_bf16(afr[i], bfr[j], acc[i][j], 0, 0, 0);
    }

    // epilogue: C/D layout col=lane&15, row=(lane>>4)*4+reg  [measured m89/m91]
    for (int i = 0; i < 4; i++) {
        size_t row0 = bm + wr + i * 16 + qd * 4;
        for (int j = 0; j < 4; j++) {
            size_t col = bn + wc + j * 16 + c;
            float bv = bias[col];
            for (int r = 0; r < 4; r++) {
                float val = acc[i][j][r] + bv;
                size_t idx = (row0 + r) * (size_t)N + col;
                if (OUTF32) ((float*)out)[idx] = val;
                else        ((unsigned short*)out)[idx] = f2b(val);
            }
        }
    }
}

// ------------- flash attention: qkv bf16 [B,T,3C] -> y bf16 [B,T,C] -------------
// Block = one (b,h,q-tile-of-64). 4 waves, wave handles 16 q-rows.
// LDS row stride 80 (= 8 mod 32 dwords pattern) keeps b128 reads at bank floor.
#define LS 80
__global__ __launch_bounds__(256) void k_attn(const unsigned short* __restrict__ qkv,
                                              unsigned short* __restrict__ y) {
    const int qi = blockIdx.x;   // q tile index, 0..31
    const int h  = blockIdx.y;
    const int b  = blockIdx.z;
    __shared__ unsigned short q_s[64 * LS];
    __shared__ unsigned short k_s[64 * LS];
    __shared__ unsigned short vT_s[64 * LS];   // vT_s[d][j]
    __shared__ unsigned short p_s[4][16 * LS];
    const int t = threadIdx.x, lane = t & 63, wave = t >> 6;
    const int c = lane & 15, qd = lane >> 4;
    const size_t rs3 = 3 * CC;
    const unsigned short* qbase = qkv + (size_t)b * TT * rs3 + h * DH;
    const unsigned short* kbase = qbase + CC;
    const unsigned short* vbase = qbase + 2 * CC;

    // stage Q (scaled by 1/sqrt(64) = 0.125, exact in bf16)
    {
        int row = t >> 2;
        for (int half = 0; half < 2; half++) {
            int col = (t & 3) * 8 + half * 32;
            ushort8 v = *(const ushort8*)(qbase + (size_t)(qi * 64 + row) * rs3 + col);
            ushort8 ov;
            for (int e = 0; e < 8; e++) ov[e] = f2b(b2f(v[e]) * 0.125f);
            *(ushort8*)&q_s[row * LS + col] = ov;
        }
    }

    float m4[4], l4[4];
    f32x4 o[4];
    for (int r = 0; r < 4; r++) { m4[r] = -__builtin_inff(); l4[r] = 0.f; }
    for (int f = 0; f < 4; f++) o[f] = (f32x4){0.f, 0.f, 0.f, 0.f};

    for (int j = 0; j <= qi; j++) {
        __syncthreads();   // protects q_s first iter + k/vT reuse
        {
            int row = t >> 2;
            for (int half = 0; half < 2; half++) {
                int col = (t & 3) * 8 + half * 32;
                ushort8 kv = *(const ushort8*)(kbase + (size_t)(j * 64 + row) * rs3 + col);
                *(ushort8*)&k_s[row * LS + col] = kv;
                ushort8 vv = *(const ushort8*)(vbase + (size_t)(j * 64 + row) * rs3 + col);
                for (int e = 0; e < 8; e++) vT_s[(col + e) * LS + row] = vv[e];   // transpose
            }
        }
        __syncthreads();

        // S = Q K^T  (wave's 16 rows x 64 kv cols), K-dim = 64 -> 2 MFMA steps
        f32x4 s[4];
        for (int f = 0; f < 4; f++) s[f] = (f32x4){0.f, 0.f, 0.f, 0.f};
        for (int step = 0; step < 2; step++) {
            bf16x8 aq = *(const bf16x8*)&q_s[(wave * 16 + c) * LS + qd * 8 + step * 32];
            for (int f = 0; f < 4; f++) {
                bf16x8 bk = *(const bf16x8*)&k_s[(f * 16 + c) * LS + qd * 8 + step * 32];
                s[f] = __builtin_amdgcn_mfma_f32_16x16x32_bf16(aq, bk, s[f], 0, 0, 0);
            }
        }
        if (j == qi) {   // causal mask inside diagonal tile
            for (int f = 0; f < 4; f++)
                for (int r = 0; r < 4; r++)
                    if (f * 16 + c > wave * 16 + qd * 4 + r) s[f][r] = -1e30f;
        }

        // online softmax; row reduction across the 16-lane group (xor 1,2,4,8)
        float pv[4][4];
        for (int r = 0; r < 4; r++) {
            float mx = fmaxf(fmaxf(s[0][r], s[1][r]), fmaxf(s[2][r], s[3][r]));
            for (int off = 1; off < 16; off <<= 1) mx = fmaxf(mx, __shfl_xor(mx, off, 64));
            float mnew = fmaxf(m4[r], mx);
            float alpha = __expf(m4[r] - mnew);   // first iter: exp(-inf)=0
            float rsum = 0.f;
            for (int f = 0; f < 4; f++) { float p = __expf(s[f][r] - mnew); pv[f][r] = p; rsum += p; }
            for (int off = 1; off < 16; off <<= 1) rsum += __shfl_xor(rsum, off, 64);
            l4[r] = l4[r] * alpha + rsum;
            m4[r] = mnew;
            for (int f = 0; f < 4; f++) o[f][r] = o[f][r] * alpha;
            for (int f = 0; f < 4; f++)
                p_s[wave][(qd * 4 + r) * LS + f * 16 + c] = f2b(pv[f][r]);   // C-layout write
        }

        // O += P V  (P read back in A-layout; wave-private p_s needs no barrier)
        for (int step = 0; step < 2; step++) {
            bf16x8 ap = *(const bf16x8*)&p_s[wave][c * LS + qd * 8 + step * 32];
            for (int f = 0; f < 4; f++) {
                bf16x8 bv = *(const bf16x8*)&vT_s[(f * 16 + c) * LS + qd * 8 + step * 32];
                o[f] = __builtin_amdgcn_mfma_f32_16x16x32_bf16(ap, bv, o[f], 0, 0, 0);
            }
        }
    }

    // normalize and write y[b, qrow, h*64+d]
    for (int f = 0; f < 4; f++)
        for (int r = 0; r < 4; r++) {
            size_t row = (size_t)b * TT + qi * 64 + wave * 16 + qd * 4 + r;
            y[row * CC + h * DH + f * 16 + c] = f2b(o[f][r] / l4[r]);
        }
}

extern "C" void kernel_launch(void* const* d_in, const int* in_sizes, int n_in,
                              void* d_out, int out_size, void* d_ws, size_t ws_size,
                              hipStream_t stream) {
    const float* x     = (const float*)d_in[0];   // [B,T,C]
    const float* Wqkv  = (const float*)d_in[1];   // [C,3C]
    const float* bqkv  = (const float*)d_in[2];   // [3C]
    const float* Wproj = (const float*)d_in[3];   // [C,C]
    const float* bproj = (const float*)d_in[4];   // [C]
    float* out = (float*)d_out;                   // [B,T,C] fp32

    const int M = BB * TT;        // 8192
    // workspace layout (bf16 = ushort). y16 aliases x16 (x dead after QKV GEMM).
    unsigned short* x16    = (unsigned short*)d_ws;          // M*C            = 8388608
    unsigned short* y16    = x16;                            // alias
    unsigned short* wqkvT  = x16 + (size_t)M * CC;           // 3C*C           = 3145728
    unsigned short* wprojT = wqkvT + (size_t)3 * CC * CC;    // C*C            = 1048576
    unsigned short* qkv16  = wprojT + (size_t)CC * CC;       // M*3C           = 25165824
    // total 37.75M ushort = 75.5 MB

    // 1. cast x to bf16
    k_f32_to_bf16<<<(M * CC) / 1024, 256, 0, stream>>>(x, x16, M * CC);
    // 2. transpose+cast weights to [N][K] bf16
    k_transpose_bf16<<<dim3(3 * CC / 32, CC / 32), dim3(32, 8), 0, stream>>>(Wqkv, wqkvT, CC, 3 * CC);
    k_transpose_bf16<<<dim3(CC / 32, CC / 32), dim3(32, 8), 0, stream>>>(Wproj, wprojT, CC, CC);
    // 3. qkv = x @ Wqkv + bqkv   (bf16 out)
    k_gemm_bt<0><<<dim3(M / 128, 3 * CC / 128), 256, 0, stream>>>(x16, wqkvT, bqkv, qkv16, M, 3 * CC, CC);
    // 4. flash attention -> y16 (overwrites x16 region)
    k_attn<<<dim3(TT / 64, HH, BB), 256, 0, stream>>>(qkv16, y16);
    // 5. out = y @ Wproj + bproj  (fp32 out)
    k_gemm_bt<1><<<dim3(M / 128, CC / 128), 256, 0, stream>>>(y16, wprojT, bproj, out, M, CC, CC);
}

// Round 2
// 338.982 us; speedup vs baseline: 1.3977x; 1.3977x over previous
//
#include <hip/hip_runtime.h>
#include <stdint.h>

#define BB 4
#define TT 2048
#define CC 1024
#define HH 16

typedef __bf16 bf16x8 __attribute__((ext_vector_type(8)));
typedef float f32x4 __attribute__((ext_vector_type(4)));
typedef float f32x16 __attribute__((ext_vector_type(16)));
typedef unsigned short ushort8 __attribute__((ext_vector_type(8)));
typedef unsigned short ushort4v __attribute__((ext_vector_type(4)));

__device__ __forceinline__ unsigned short f2b(float f) {
    union { float f; unsigned u; } v; v.f = f;
    unsigned r = v.u + 0x7FFFu + ((v.u >> 16) & 1u);   // RNE
    return (unsigned short)(r >> 16);
}
__device__ __forceinline__ float b2f(unsigned short s) {
    union { unsigned u; float f; } v; v.u = ((unsigned)s) << 16;
    return v.f;
}

// async global->LDS, 16B per lane; lds dest = wave-uniform(readfirstlane) base + lane*16
#define ASYNC16(gp, lp) __builtin_amdgcn_global_load_lds( \
    (const __attribute__((address_space(1))) void*)(gp),  \
    (__attribute__((address_space(3))) void*)(lp), 16, 0, 0)

// ---------------- fp32 -> bf16 cast ----------------
__global__ __launch_bounds__(256) void k_cast(const float* __restrict__ in,
                                              unsigned short* __restrict__ out, int n) {
    int i = (blockIdx.x * 256 + threadIdx.x) * 4;
    if (i >= n) return;
    float4 v = *(const float4*)(in + i);
    ushort4v o;
    o.x = f2b(v.x); o.y = f2b(v.y); o.z = f2b(v.z); o.w = f2b(v.w);
    *(ushort4v*)(out + i) = o;
}

// ------------- transpose + cast: fp32 [R][Cc] -> bf16 [Cc][R] -------------
__global__ __launch_bounds__(256) void k_transpose_bf16(const float* __restrict__ in,
                                                        unsigned short* __restrict__ out,
                                                        int R, int Cc) {
    __shared__ float tile[32][33];
    int bx = blockIdx.x * 32, by = blockIdx.y * 32;
    int tx = threadIdx.x, ty = threadIdx.y;   // (32, 8)
    for (int i = 0; i < 32; i += 8)
        tile[ty + i][tx] = in[(size_t)(by + ty + i) * Cc + bx + tx];
    __syncthreads();
    for (int i = 0; i < 32; i += 8)
        out[(size_t)(bx + ty + i) * R + by + tx] = f2b(tile[tx][ty + i]);
}

// ------------- bf16 MFMA GEMM: 128x128 tile, BK=32, async staging (m97 structure) -------------
// MODE 0: out = fp32 d_out + bias (proj). MODE 1: qkv -> split q16(scaled)/k16/vT16.
#define QSCALE 0.125f
template <int MODE>
__global__ __launch_bounds__(256) void k_gemm(const unsigned short* __restrict__ A,
                                              const unsigned short* __restrict__ Bt,
                                              const float* __restrict__ bias,
                                              float* __restrict__ outf,
                                              unsigned short* __restrict__ qo,
                                              unsigned short* __restrict__ ko,
                                              unsigned short* __restrict__ vo,
                                              int M, int N, int K) {
    __shared__ unsigned short As[128 * 32];
    __shared__ unsigned short Bs[128 * 32];
    const int t = threadIdx.x;
    const int lane = t & 63;
    const int c = lane & 15, qd = lane >> 4;
    const int wave = t >> 6;
    const int wr = (wave >> 1) * 64, wc = (wave & 1) * 64;
    const int bm = blockIdx.x * 128, bn = blockIdx.y * 128;

    f32x4 acc[4][4] = {};

    // per-lane staging addrs; LDS elem = t*8 (lane-contiguous => valid global_load_lds dest)
    const unsigned short* Ap = A + (size_t)(bm + (t >> 2)) * K + (t & 3) * 8;
    const unsigned short* Bp = Bt + (size_t)(bn + (t >> 2)) * K + (t & 3) * 8;
    unsigned short* Asw = &As[t * 8];
    unsigned short* Bsw = &Bs[t * 8];

    for (int k0 = 0; k0 < K; k0 += 32) {
        __syncthreads();                       // prev iter's LDS reads done
        ASYNC16(Ap + k0, Asw);
        ASYNC16(Ap + (size_t)64 * K + k0, Asw + 2048);
        ASYNC16(Bp + k0, Bsw);
        ASYNC16(Bp + (size_t)64 * K + k0, Bsw + 2048);
        __syncthreads();                       // drains vmcnt -> tiles visible
        bf16x8 af[4], bfr[4];
        for (int i = 0; i < 4; i++)
            af[i] = *(const bf16x8*)&As[(wr + i * 16 + c) * 32 + qd * 8];
        for (int j = 0; j < 4; j++)
            bfr[j] = *(const bf16x8*)&Bs[(wc + j * 16 + c) * 32 + qd * 8];
        for (int i = 0; i < 4; i++)
            for (int j = 0; j < 4; j++)
                acc[i][j] = __builtin_amdgcn_mfma_f32_16x16x32_bf16(af[i], bfr[j], acc[i][j], 0, 0, 0);
    }

    // epilogue: C/D layout col=lane&15, row=qd*4+reg [m89/m91]
    if (MODE == 0) {
        for (int i = 0; i < 4; i++) {
            int row0 = bm + wr + i * 16 + qd * 4;
            for (int j = 0; j < 4; j++) {
                int col = bn + wc + j * 16 + c;
                float bv = bias[col];
                for (int r = 0; r < 4; r++)
                    outf[(size_t)(row0 + r) * N + col] = acc[i][j][r] + bv;
            }
        }
    } else {
        if (bn < 1024) {              // Q segment, pre-scaled by 1/sqrt(64)
            for (int i = 0; i < 4; i++) {
                int row0 = bm + wr + i * 16 + qd * 4;
                for (int j = 0; j < 4; j++) {
                    int col = bn + wc + j * 16 + c;
                    float bv = bias[col];
                    for (int r = 0; r < 4; r++)
                        qo[(size_t)(row0 + r) * 1024 + col] = f2b((acc[i][j][r] + bv) * QSCALE);
                }
            }
        } else if (bn < 2048) {       // K segment
            for (int i = 0; i < 4; i++) {
                int row0 = bm + wr + i * 16 + qd * 4;
                for (int j = 0; j < 4; j++) {
                    int col = bn + wc + j * 16 + c;
                    float bv = bias[col];
                    for (int r = 0; r < 4; r++)
                        ko[(size_t)(row0 + r) * 1024 + (col - 1024)] = f2b(acc[i][j][r] + bv);
                }
            }
        } else {                      // V segment -> vT16[(b*16+h)*64+d][t], packed 4 rows (=4 t)
            int b = bm >> 11;
            int tb = (bm & 2047) + wr;
            for (int i = 0; i < 4; i++) {
                int t0 = tb + i * 16 + qd * 4;
                for (int j = 0; j < 4; j++) {
                    int col = bn + wc + j * 16 + c;
                    float bv = bias[col];
                    int d = col - 2048;
                    int hh = d >> 6, dl = d & 63;
                    ushort4v pk;
                    pk.x = f2b(acc[i][j][0] + bv); pk.y = f2b(acc[i][j][1] + bv);
                    pk.z = f2b(acc[i][j][2] + bv); pk.w = f2b(acc[i][j][3] + bv);
                    *(ushort4v*)&vo[(((size_t)b * 16 + hh) * 64 + dl) * TT + t0] = pk;
                }
            }
        }
    }
}

// ------------- flash attention, S^T formulation, 32x32x16 MFMA -------------
// block = (qi 128-row q-tile, h, b); 4 waves x 32 q each; kv-tile 64.
// S^T = K*Q^T  => C-layout: lane's q = lane&31, kv spread over 16 regs + lane>>5.
// O^T = V^T*P^T; V^T pre-transposed in global by GEMM epilogue.
// 32x32x16 frags: A[m=lane&31][k=(lane>>5)*8+e], B[k=(lane>>5)*8+e][n=lane&31],
// C/D: col=lane&31, row=(reg&3)+8*(reg>>2)+4*(lane>>5)  [m74/m101]
__global__ __launch_bounds__(256) void k_attn(const unsigned short* __restrict__ q16,
                                              const unsigned short* __restrict__ k16,
                                              const unsigned short* __restrict__ vT16,
                                              unsigned short* __restrict__ y16) {
    const int qi = 15 - (int)blockIdx.x;   // heavy blocks first
    const int h = blockIdx.y, b = blockIdx.z;
    __shared__ unsigned short q_s[128 * 72];   // [q][d]
    __shared__ unsigned short k_s[64 * 72];    // [kv][d]
    __shared__ unsigned short vt_s[64 * 72];   // [d][kv]
    __shared__ unsigned short p_s[4][32 * 72]; // per-wave [q][kv]
    const int t = threadIdx.x, lane = t & 63, wave = t >> 6;
    const int l31 = lane & 31, hl = lane >> 5;
    const int wq = wave * 32;

    // stage Q tile 128x64 (already scaled): thread t -> row t>>1, 32-elem half
    {
        int row = t >> 1, c32 = (t & 1) * 32;
        const unsigned short* src = q16 + ((size_t)(b * TT + qi * 128 + row)) * CC + h * 64 + c32;
        ushort8 v0 = *(const ushort8*)(src);
        ushort8 v1 = *(const ushort8*)(src + 8);
        ushort8 v2 = *(const ushort8*)(src + 16);
        ushort8 v3 = *(const ushort8*)(src + 24);
        *(ushort8*)&q_s[row * 72 + c32] = v0;
        *(ushort8*)&q_s[row * 72 + c32 + 8] = v1;
        *(ushort8*)&q_s[row * 72 + c32 + 16] = v2;
        *(ushort8*)&q_s[row * 72 + c32 + 24] = v3;
    }
    __syncthreads();
    // hoist Q B-frags (constant over kv loop): 4 d-steps
    bf16x8 qf[4];
    for (int s = 0; s < 4; s++)
        qf[s] = *(const bf16x8*)&q_s[(wq + l31) * 72 + s * 16 + hl * 8];

    f32x16 oacc[2] = {};
    float m = -3e38f, l = 0.f;
    const int qmaxw = qi * 128 + wq + 31;
    const int qminw = qi * 128 + wq;
    const int qg = qi * 128 + wq + l31;
    const int jn = 2 * qi + 2;
    const unsigned short* kbase = k16 + (size_t)b * TT * CC + h * 64;
    const unsigned short* vbase = vT16 + (((size_t)b * 16 + h) * 64) * TT;

    for (int j = 0; j < jn; j++) {
        // stage K (64x64) and V^T (64x64): thread t -> row t>>2, 16-elem chunk
        int row = t >> 2, c16 = (t & 3) * 16;
        const unsigned short* ksrc = kbase + (size_t)(j * 64 + row) * CC + c16;
        const unsigned short* vsrc = vbase + (size_t)row * TT + j * 64 + c16;
        ushort8 ka = *(const ushort8*)ksrc, kb = *(const ushort8*)(ksrc + 8);
        ushort8 va = *(const ushort8*)vsrc, vb = *(const ushort8*)(vsrc + 8);
        __syncthreads();   // all waves done reading prev k_s/vt_s
        *(ushort8*)&k_s[row * 72 + c16] = ka;
        *(ushort8*)&k_s[row * 72 + c16 + 8] = kb;
        *(ushort8*)&vt_s[row * 72 + c16] = va;
        *(ushort8*)&vt_s[row * 72 + c16 + 8] = vb;
        __syncthreads();
        if (j * 64 > qmaxw) continue;   // tile fully masked for this wave (wave-uniform)

        // S^T = K * Q^T : 2 kv-chunks x 4 d-steps
        f32x16 sacc[2] = {};
        for (int c2 = 0; c2 < 2; c2++)
            for (int s = 0; s < 4; s++) {
                bf16x8 kf = *(const bf16x8*)&k_s[(c2 * 32 + l31) * 72 + s * 16 + hl * 8];
                sacc[c2] = __builtin_amdgcn_mfma_f32_32x32x16_bf16(kf, qf[s], sacc[c2], 0, 0, 0);
            }

        if (j * 64 + 63 > qminw) {   // partial tile: element mask kv > q
            for (int c2 = 0; c2 < 2; c2++)
                for (int r = 0; r < 16; r++) {
                    int kvg = j * 64 + c2 * 32 + (r & 3) + 8 * (r >> 2) + 4 * hl;
                    if (kvg > qg) sacc[c2][r] = -3e38f;
                }
        }

        // online softmax: all 32 kv values of lane's q are in-lane (+ partner lane^32)
        float mx = -3e38f;
        for (int c2 = 0; c2 < 2; c2++)
            for (int r = 0; r < 16; r++) mx = fmaxf(mx, sacc[c2][r]);
        mx = fmaxf(mx, __shfl_xor(mx, 32, 64));
        float mn = fmaxf(m, mx);
        float alpha = __expf(m - mn);
        float sum = 0.f;
        for (int c2 = 0; c2 < 2; c2++)
            for (int g = 0; g < 4; g++) {
                float p0 = __expf(sacc[c2][g * 4 + 0] - mn);
                float p1 = __expf(sacc[c2][g * 4 + 1] - mn);
                float p2 = __expf(sacc[c2][g * 4 + 2] - mn);
                float p3 = __expf(sacc[c2][g * 4 + 3] - mn);
                sum += (p0 + p1) + (p2 + p3);
                ushort4v pk; pk.x = f2b(p0); pk.y = f2b(p1); pk.z = f2b(p2); pk.w = f2b(p3);
                // kv = c2*32 + 8g + 4hl + (0..3), q row = l31  -> b64 store, 4-way floor
                *(ushort4v*)&p_s[wave][l31 * 72 + c2 * 32 + g * 8 + hl * 4] = pk;
            }
        sum += __shfl_xor(sum, 32, 64);
        l = l * alpha + sum;
        m = mn;
        for (int c2 = 0; c2 < 2; c2++)
            for (int r = 0; r < 16; r++) oacc[c2][r] *= alpha;

        // O^T += V^T * P^T : 2 d-chunks x 4 kv-steps; P frags shared across d-chunks
        for (int s = 0; s < 4; s++) {
            bf16x8 pf = *(const bf16x8*)&p_s[wave][l31 * 72 + s * 16 + hl * 8];
            for (int c2 = 0; c2 < 2; c2++) {
                bf16x8 vf = *(const bf16x8*)&vt_s[(c2 * 32 + l31) * 72 + s * 16 + hl * 8];
                oacc[c2] = __builtin_amdgcn_mfma_f32_32x32x16_bf16(vf, pf, oacc[c2], 0, 0, 0);
            }
        }
    }

    // epilogue: y[token=qg][h*64 + d], d = c2*32 + 8g + 4hl + r -> 4-elem packs
    float rl = 1.0f / l;
    size_t rowb = ((size_t)b * TT + qg) * CC + h * 64;
    for (int c2 = 0; c2 < 2; c2++)
        for (int g = 0; g < 4; g++) {
            ushort4v pk;
            pk.x = f2b(oacc[c2][g * 4 + 0] * rl);
            pk.y = f2b(oacc[c2][g * 4 + 1] * rl);
            pk.z = f2b(oacc[c2][g * 4 + 2] * rl);
            pk.w = f2b(oacc[c2][g * 4 + 3] * rl);
            *(ushort4v*)&y16[rowb + c2 * 32 + g * 8 + hl * 4] = pk;
        }
}

extern "C" void kernel_launch(void* const* d_in, const int* in_sizes, int n_in,
                              void* d_out, int out_size, void* d_ws, size_t ws_size,
                              hipStream_t stream) {
    const float* x     = (const float*)d_in[0];
    const float* Wqkv  = (const float*)d_in[1];
    const float* bqkv  = (const float*)d_in[2];
    const float* Wproj = (const float*)d_in[3];
    const float* bproj = (const float*)d_in[4];
    float* out = (float*)d_out;

    const int M = BB * TT;   // 8192
    unsigned short* x16    = (unsigned short*)d_ws;          // M*C
    unsigned short* y16    = x16;                            // alias (x dead after GEMM1)
    unsigned short* wqkvT  = x16 + (size_t)M * CC;           // 3C*C
    unsigned short* wprojT = wqkvT + (size_t)3 * CC * CC;    // C*C
    unsigned short* q16    = wprojT + (size_t)CC * CC;       // M*C (scaled)
    unsigned short* k16    = q16 + (size_t)M * CC;           // M*C
    unsigned short* vT16   = k16 + (size_t)M * CC;           // [B*H][64][T] = M*C
    // total 37.75M ushort = 75.5 MB (same as R1)

    k_cast<<<(M * CC) / 1024, 256, 0, stream>>>(x, x16, M * CC);
    k_transpose_bf16<<<dim3(3 * CC / 32, CC / 32), dim3(32, 8), 0, stream>>>(Wqkv, wqkvT, CC, 3 * CC);
    k_transpose_bf16<<<dim3(CC / 32, CC / 32), dim3(32, 8), 0, stream>>>(Wproj, wprojT, CC, CC);
    k_gemm<1><<<dim3(M / 128, 3 * CC / 128), 256, 0, stream>>>(x16, wqkvT, bqkv, nullptr,
                                                               q16, k16, vT16, M, 3 * CC, CC);
    k_attn<<<dim3(TT / 128, HH, BB), 256, 0, stream>>>(q16, k16, vT16, y16);
    k_gemm<0><<<dim3(M / 128, CC / 128), 256, 0, stream>>>(y16, wprojT, bproj, out,
                                                           nullptr, nullptr, nullptr, M, CC, CC);
}

// Round 3
// 320.923 us; speedup vs baseline: 1.4764x; 1.0563x over previous
//
#include <hip/hip_runtime.h>
#include <stdint.h>

#define BB 4
#define TT 2048
#define CC 1024
#define HH 16

typedef __bf16 bf16x8 __attribute__((ext_vector_type(8)));
typedef float f32x4 __attribute__((ext_vector_type(4)));
typedef float f32x16 __attribute__((ext_vector_type(16)));
typedef unsigned short ushort8 __attribute__((ext_vector_type(8)));
typedef unsigned short ushort4v __attribute__((ext_vector_type(4)));

__device__ __forceinline__ unsigned short f2b(float f) {
    union { float f; unsigned u; } v; v.f = f;
    unsigned r = v.u + 0x7FFFu + ((v.u >> 16) & 1u);   // RNE
    return (unsigned short)(r >> 16);
}
// pack two positive floats to bf16x2 (round-half-up) in one v_perm each
__device__ __forceinline__ unsigned pack2(float a, float b) {
    union { float f; unsigned u; } ua, ub; ua.f = a; ub.f = b;
    return __builtin_amdgcn_perm(ub.u + 0x8000u, ua.u + 0x8000u, 0x07060302u);
}

// async global->LDS, 16B per lane
#define ASYNC16(gp, lp) __builtin_amdgcn_global_load_lds( \
    (const __attribute__((address_space(1))) void*)(gp),  \
    (__attribute__((address_space(3))) void*)(lp), 16, 0, 0)

// ---------------- fp32 -> bf16 cast ----------------
__global__ __launch_bounds__(256) void k_cast(const float* __restrict__ in,
                                              unsigned short* __restrict__ out, int n) {
    int i = (blockIdx.x * 256 + threadIdx.x) * 4;
    if (i >= n) return;
    float4 v = *(const float4*)(in + i);
    ushort4v o;
    o.x = f2b(v.x); o.y = f2b(v.y); o.z = f2b(v.z); o.w = f2b(v.w);
    *(ushort4v*)(out + i) = o;
}

// ------------- transpose + cast: fp32 [R][Cc] -> bf16 [Cc][R] -------------
__global__ __launch_bounds__(256) void k_transpose_bf16(const float* __restrict__ in,
                                                        unsigned short* __restrict__ out,
                                                        int R, int Cc) {
    __shared__ float tile[32][33];
    int bx = blockIdx.x * 32, by = blockIdx.y * 32;
    int tx = threadIdx.x, ty = threadIdx.y;   // (32, 8)
    for (int i = 0; i < 32; i += 8)
        tile[ty + i][tx] = in[(size_t)(by + ty + i) * Cc + bx + tx];
    __syncthreads();
    for (int i = 0; i < 32; i += 8)
        out[(size_t)(bx + ty + i) * R + by + tx] = f2b(tile[tx][ty + i]);
}

// ------------- bf16 MFMA GEMM: 128x128 tile, BK=32, async staging (m97 structure) -------------
#define QSCALE 0.125f
template <int MODE>
__global__ __launch_bounds__(256) void k_gemm(const unsigned short* __restrict__ A,
                                              const unsigned short* __restrict__ Bt,
                                              const float* __restrict__ bias,
                                              float* __restrict__ outf,
                                              unsigned short* __restrict__ qo,
                                              unsigned short* __restrict__ ko,
                                              unsigned short* __restrict__ vo,
                                              int M, int N, int K) {
    __shared__ unsigned short As[128 * 32];
    __shared__ unsigned short Bs[128 * 32];
    const int t = threadIdx.x;
    const int lane = t & 63;
    const int c = lane & 15, qd = lane >> 4;
    const int wave = t >> 6;
    const int wr = (wave >> 1) * 64, wc = (wave & 1) * 64;
    const int bm = blockIdx.x * 128, bn = blockIdx.y * 128;

    f32x4 acc[4][4] = {};

    const unsigned short* Ap = A + (size_t)(bm + (t >> 2)) * K + (t & 3) * 8;
    const unsigned short* Bp = Bt + (size_t)(bn + (t >> 2)) * K + (t & 3) * 8;
    unsigned short* Asw = &As[t * 8];
    unsigned short* Bsw = &Bs[t * 8];

    for (int k0 = 0; k0 < K; k0 += 32) {
        __syncthreads();
        ASYNC16(Ap + k0, Asw);
        ASYNC16(Ap + (size_t)64 * K + k0, Asw + 2048);
        ASYNC16(Bp + k0, Bsw);
        ASYNC16(Bp + (size_t)64 * K + k0, Bsw + 2048);
        __syncthreads();
        bf16x8 af[4], bfr[4];
        for (int i = 0; i < 4; i++)
            af[i] = *(const bf16x8*)&As[(wr + i * 16 + c) * 32 + qd * 8];
        for (int j = 0; j < 4; j++)
            bfr[j] = *(const bf16x8*)&Bs[(wc + j * 16 + c) * 32 + qd * 8];
        for (int i = 0; i < 4; i++)
            for (int j = 0; j < 4; j++)
                acc[i][j] = __builtin_amdgcn_mfma_f32_16x16x32_bf16(af[i], bfr[j], acc[i][j], 0, 0, 0);
    }

    if (MODE == 0) {
        for (int i = 0; i < 4; i++) {
            int row0 = bm + wr + i * 16 + qd * 4;
            for (int j = 0; j < 4; j++) {
                int col = bn + wc + j * 16 + c;
                float bv = bias[col];
                for (int r = 0; r < 4; r++)
                    outf[(size_t)(row0 + r) * N + col] = acc[i][j][r] + bv;
            }
        }
    } else {
        if (bn < 1024) {              // Q, pre-scaled
            for (int i = 0; i < 4; i++) {
                int row0 = bm + wr + i * 16 + qd * 4;
                for (int j = 0; j < 4; j++) {
                    int col = bn + wc + j * 16 + c;
                    float bv = bias[col];
                    for (int r = 0; r < 4; r++)
                        qo[(size_t)(row0 + r) * 1024 + col] = f2b((acc[i][j][r] + bv) * QSCALE);
                }
            }
        } else if (bn < 2048) {       // K
            for (int i = 0; i < 4; i++) {
                int row0 = bm + wr + i * 16 + qd * 4;
                for (int j = 0; j < 4; j++) {
                    int col = bn + wc + j * 16 + c;
                    float bv = bias[col];
                    for (int r = 0; r < 4; r++)
                        ko[(size_t)(row0 + r) * 1024 + (col - 1024)] = f2b(acc[i][j][r] + bv);
                }
            }
        } else {                      // V -> vT16[(b*16+h)*64+d][t]; L2 merges the 8B scatters
            int b = bm >> 11;
            int tb = (bm & 2047) + wr;
            for (int i = 0; i < 4; i++) {
                int t0 = tb + i * 16 + qd * 4;
                for (int j = 0; j < 4; j++) {
                    int col = bn + wc + j * 16 + c;
                    float bv = bias[col];
                    int d = col - 2048;
                    int hh = d >> 6, dl = d & 63;
                    ushort4v pk;
                    pk.x = f2b(acc[i][j][0] + bv); pk.y = f2b(acc[i][j][1] + bv);
                    pk.z = f2b(acc[i][j][2] + bv); pk.w = f2b(acc[i][j][3] + bv);
                    *(ushort4v*)&vo[(((size_t)b * 16 + hh) * 64 + dl) * TT + t0] = pk;
                }
            }
        }
    }
}

// ------------- flash attention, S^T form, 32x32x16 MFMA, no p_s, pipelined staging -------------
// 32x32x16 frags: A[m=lane&31][k=(lane>>5)*8+e], B[k=(lane>>5)*8+e][n=lane&31],
// C/D: col=lane&31, row=(reg&3)+8*(reg>>2)+4*(lane>>5)  [m74/m101]
__global__ __launch_bounds__(256, 4) void k_attn(const unsigned short* __restrict__ q16,
                                                 const unsigned short* __restrict__ k16,
                                                 const unsigned short* __restrict__ vT16,
                                                 unsigned short* __restrict__ y16) {
    const int h = blockIdx.y, b = blockIdx.z;
    const int pi = ((int)blockIdx.x + h) & 15;                 // balance swizzle
    const int qi = (pi & 1) ? (pi >> 1) : (15 - (pi >> 1));    // heavy/light interleave
    __shared__ unsigned short q_s[128 * 72];   // [q][d]
    __shared__ unsigned short k_s[64 * 72];    // [kv][d]
    __shared__ unsigned short vt_s[64 * 72];   // [d][kv]
    const int t = threadIdx.x, lane = t & 63, wave = t >> 6;
    const int l31 = lane & 31, hl = lane >> 5;
    const int wq = wave * 32;

    // stage Q tile 128x64 (already scaled)
    {
        int row = t >> 1, c32 = (t & 1) * 32;
        const unsigned short* src = q16 + ((size_t)(b * TT + qi * 128 + row)) * CC + h * 64 + c32;
        ushort8 v0 = *(const ushort8*)(src);
        ushort8 v1 = *(const ushort8*)(src + 8);
        ushort8 v2 = *(const ushort8*)(src + 16);
        ushort8 v3 = *(const ushort8*)(src + 24);
        *(ushort8*)&q_s[row * 72 + c32] = v0;
        *(ushort8*)&q_s[row * 72 + c32 + 8] = v1;
        *(ushort8*)&q_s[row * 72 + c32 + 16] = v2;
        *(ushort8*)&q_s[row * 72 + c32 + 24] = v3;
    }
    __syncthreads();
    bf16x8 qf[4];
    for (int s = 0; s < 4; s++)
        qf[s] = *(const bf16x8*)&q_s[(wq + l31) * 72 + s * 16 + hl * 8];

    f32x16 oacc[2] = {};
    float m = -3e38f, l = 0.f;
    const int qmaxw = qi * 128 + wq + 31;
    const int qminw = qi * 128 + wq;
    const int qg = qi * 128 + wq + l31;
    const int jn = 2 * qi + 2;
    const unsigned short* kbase = k16 + (size_t)b * TT * CC + h * 64;
    const unsigned short* vbase = vT16 + (((size_t)b * 16 + h) * 64) * TT;

    // staging addresses + prologue prefetch of tile j=0
    const int row = t >> 2, c16 = (t & 3) * 16;
    const unsigned short* ksrc = kbase + (size_t)row * CC + c16;
    const unsigned short* vsrc = vbase + (size_t)row * TT + c16;
    ushort8 ka = *(const ushort8*)ksrc, kb = *(const ushort8*)(ksrc + 8);
    ushort8 va = *(const ushort8*)vsrc, vb = *(const ushort8*)(vsrc + 8);

    for (int j = 0; j < jn; j++) {
        __syncthreads();   // all waves done reading prev k_s/vt_s
        *(ushort8*)&k_s[row * 72 + c16] = ka;
        *(ushort8*)&k_s[row * 72 + c16 + 8] = kb;
        *(ushort8*)&vt_s[row * 72 + c16] = va;
        *(ushort8*)&vt_s[row * 72 + c16 + 8] = vb;
        __syncthreads();
        if (j + 1 < jn) {   // prefetch next tile; latency hides behind compute below
            const unsigned short* kn = ksrc + (size_t)(j + 1) * 64 * CC;
            const unsigned short* vn = vsrc + (j + 1) * 64;
            ka = *(const ushort8*)kn; kb = *(const ushort8*)(kn + 8);
            va = *(const ushort8*)vn; vb = *(const ushort8*)(vn + 8);
        }
        if (j * 64 > qmaxw) continue;   // fully-masked for this wave (wave-uniform)

        // S^T = K * Q^T
        f32x16 sacc[2] = {};
        for (int c2 = 0; c2 < 2; c2++)
            for (int s = 0; s < 4; s++) {
                bf16x8 kf = *(const bf16x8*)&k_s[(c2 * 32 + l31) * 72 + s * 16 + hl * 8];
                sacc[c2] = __builtin_amdgcn_mfma_f32_32x32x16_bf16(kf, qf[s], sacc[c2], 0, 0, 0);
            }

        if (j * 64 + 63 > qminw) {   // diagonal tile: mask kv > q
            for (int c2 = 0; c2 < 2; c2++)
                for (int r = 0; r < 16; r++) {
                    int kvg = j * 64 + c2 * 32 + (r & 3) + 8 * (r >> 2) + 4 * hl;
                    if (kvg > qg) sacc[c2][r] = -1e30f;
                }
        }

        // online softmax (all kv of lane's q in-lane + partner lane^32)
        float mx = -1e30f;
        for (int c2 = 0; c2 < 2; c2++)
            for (int r = 0; r < 16; r++) mx = fmaxf(mx, sacc[c2][r]);
        mx = fmaxf(mx, __shfl_xor(mx, 32, 64));
        float mn = fmaxf(m, mx);
        float alpha = __expf(m - mn);
        m = mn;
        float sum = 0.f;
        unsigned pg[2][4][2];
        for (int c2 = 0; c2 < 2; c2++)
            for (int g = 0; g < 4; g++) {
                float p0 = __expf(sacc[c2][g * 4 + 0] - mn);
                float p1 = __expf(sacc[c2][g * 4 + 1] - mn);
                float p2 = __expf(sacc[c2][g * 4 + 2] - mn);
                float p3 = __expf(sacc[c2][g * 4 + 3] - mn);
                sum += (p0 + p1) + (p2 + p3);
                pg[c2][g][0] = pack2(p0, p1);
                pg[c2][g][1] = pack2(p2, p3);
            }
        sum += __shfl_xor(sum, 32, 64);
        l = l * alpha + sum;
        for (int c2 = 0; c2 < 2; c2++)
            for (int r = 0; r < 16; r++) oacc[c2][r] *= alpha;

        // C-layout -> B-operand layout: half-swap with partner lane (lane^32)
        bf16x8 pf[4];
        for (int c2 = 0; c2 < 2; c2++)
            for (int pr = 0; pr < 2; pr++) {
                unsigned se0 = hl ? pg[c2][2 * pr][0] : pg[c2][2 * pr + 1][0];
                unsigned se1 = hl ? pg[c2][2 * pr][1] : pg[c2][2 * pr + 1][1];
                unsigned r0 = (unsigned)__shfl_xor((int)se0, 32, 64);
                unsigned r1 = (unsigned)__shfl_xor((int)se1, 32, 64);
                union { unsigned u[4]; bf16x8 v; } fr;
                fr.u[0] = hl ? r0 : pg[c2][2 * pr][0];
                fr.u[1] = hl ? r1 : pg[c2][2 * pr][1];
                fr.u[2] = hl ? pg[c2][2 * pr + 1][0] : r0;
                fr.u[3] = hl ? pg[c2][2 * pr + 1][1] : r1;
                pf[c2 * 2 + pr] = fr.v;
            }

        // O^T += V^T * P^T
        for (int s = 0; s < 4; s++)
            for (int c2o = 0; c2o < 2; c2o++) {
                bf16x8 vf = *(const bf16x8*)&vt_s[(c2o * 32 + l31) * 72 + s * 16 + hl * 8];
                oacc[c2o] = __builtin_amdgcn_mfma_f32_32x32x16_bf16(vf, pf[s], oacc[c2o], 0, 0, 0);
            }
    }

    // epilogue: y[token=qg][h*64 + d]
    float rl = 1.0f / l;
    size_t rowb = ((size_t)b * TT + qg) * CC + h * 64;
    for (int c2 = 0; c2 < 2; c2++)
        for (int g = 0; g < 4; g++) {
            ushort4v pk;
            pk.x = f2b(oacc[c2][g * 4 + 0] * rl);
            pk.y = f2b(oacc[c2][g * 4 + 1] * rl);
            pk.z = f2b(oacc[c2][g * 4 + 2] * rl);
            pk.w = f2b(oacc[c2][g * 4 + 3] * rl);
            *(ushort4v*)&y16[rowb + c2 * 32 + g * 8 + hl * 4] = pk;
        }
}

extern "C" void kernel_launch(void* const* d_in, const int* in_sizes, int n_in,
                              void* d_out, int out_size, void* d_ws, size_t ws_size,
                              hipStream_t stream) {
    const float* x     = (const float*)d_in[0];
    const float* Wqkv  = (const float*)d_in[1];
    const float* bqkv  = (const float*)d_in[2];
    const float* Wproj = (const float*)d_in[3];
    const float* bproj = (const float*)d_in[4];
    float* out = (float*)d_out;

    const int M = BB * TT;   // 8192
    unsigned short* x16    = (unsigned short*)d_ws;          // M*C
    unsigned short* y16    = x16;                            // alias (x dead after GEMM1)
    unsigned short* wqkvT  = x16 + (size_t)M * CC;           // 3C*C
    unsigned short* wprojT = wqkvT + (size_t)3 * CC * CC;    // C*C
    unsigned short* q16    = wprojT + (size_t)CC * CC;       // M*C (scaled)
    unsigned short* k16    = q16 + (size_t)M * CC;           // M*C
    unsigned short* vT16   = k16 + (size_t)M * CC;           // [B*H][64][T] = M*C

    k_cast<<<(M * CC) / 1024, 256, 0, stream>>>(x, x16, M * CC);
    k_transpose_bf16<<<dim3(3 * CC / 32, CC / 32), dim3(32, 8), 0, stream>>>(Wqkv, wqkvT, CC, 3 * CC);
    k_transpose_bf16<<<dim3(CC / 32, CC / 32), dim3(32, 8), 0, stream>>>(Wproj, wprojT, CC, CC);
    k_gemm<1><<<dim3(M / 128, 3 * CC / 128), 256, 0, stream>>>(x16, wqkvT, bqkv, nullptr,
                                                               q16, k16, vT16, M, 3 * CC, CC);
    k_attn<<<dim3(TT / 128, HH, BB), 256, 0, stream>>>(q16, k16, vT16, y16);
    k_gemm<0><<<dim3(M / 128, CC / 128), 256, 0, stream>>>(y16, wprojT, bproj, out,
                                                           nullptr, nullptr, nullptr, M, CC, CC);
}

// Round 4
// 281.225 us; speedup vs baseline: 1.6848x; 1.1412x over previous
//
#include <hip/hip_runtime.h>
#include <stdint.h>

#define BB 4
#define TT 2048
#define CC 1024
#define HH 16

typedef __bf16 bf16x8 __attribute__((ext_vector_type(8)));
typedef float f32x4 __attribute__((ext_vector_type(4)));
typedef float f32x16 __attribute__((ext_vector_type(16)));
typedef unsigned short ushort8 __attribute__((ext_vector_type(8)));
typedef unsigned short ushort4v __attribute__((ext_vector_type(4)));

__device__ __forceinline__ unsigned short f2b(float f) {
    union { float f; unsigned u; } v; v.f = f;
    unsigned r = v.u + 0x7FFFu + ((v.u >> 16) & 1u);   // RNE
    return (unsigned short)(r >> 16);
}
// pack two positive floats to bf16x2 (round-half-up) in one v_perm each
__device__ __forceinline__ unsigned pack2(float a, float b) {
    union { float f; unsigned u; } ua, ub; ua.f = a; ub.f = b;
    return __builtin_amdgcn_perm(ub.u + 0x8000u, ua.u + 0x8000u, 0x07060302u);
}
__device__ __forceinline__ float fexp2(float x) {
#if __has_builtin(__builtin_amdgcn_exp2f)
    return __builtin_amdgcn_exp2f(x);
#else
    return exp2f(x);
#endif
}
#define LOG2E 1.4426950408889634f

// async global->LDS, 16B per lane
#define ASYNC16(gp, lp) __builtin_amdgcn_global_load_lds( \
    (const __attribute__((address_space(1))) void*)(gp),  \
    (__attribute__((address_space(3))) void*)(lp), 16, 0, 0)

// ---------------- fp32 -> bf16 cast ----------------
__global__ __launch_bounds__(256) void k_cast(const float* __restrict__ in,
                                              unsigned short* __restrict__ out, int n) {
    int i = (blockIdx.x * 256 + threadIdx.x) * 4;
    if (i >= n) return;
    float4 v = *(const float4*)(in + i);
    ushort4v o;
    o.x = f2b(v.x); o.y = f2b(v.y); o.z = f2b(v.z); o.w = f2b(v.w);
    *(ushort4v*)(out + i) = o;
}

// ------------- transpose + cast: fp32 [R][Cc] -> bf16 [Cc][R] -------------
__global__ __launch_bounds__(256) void k_transpose_bf16(const float* __restrict__ in,
                                                        unsigned short* __restrict__ out,
                                                        int R, int Cc) {
    __shared__ float tile[32][33];
    int bx = blockIdx.x * 32, by = blockIdx.y * 32;
    int tx = threadIdx.x, ty = threadIdx.y;   // (32, 8)
    for (int i = 0; i < 32; i += 8)
        tile[ty + i][tx] = in[(size_t)(by + ty + i) * Cc + bx + tx];
    __syncthreads();
    for (int i = 0; i < 32; i += 8)
        out[(size_t)(bx + ty + i) * R + by + tx] = f2b(tile[tx][ty + i]);
}

// ------------- bf16 MFMA GEMM: 128x128 tile, BK=32, async staging (m97 structure) -------------
#define QSCALE 0.125f
template <int MODE>
__global__ __launch_bounds__(256) void k_gemm(const unsigned short* __restrict__ A,
                                              const unsigned short* __restrict__ Bt,
                                              const float* __restrict__ bias,
                                              float* __restrict__ outf,
                                              unsigned short* __restrict__ qo,
                                              unsigned short* __restrict__ ko,
                                              unsigned short* __restrict__ vo,
                                              int M, int N, int K) {
    __shared__ unsigned short As[128 * 32];
    __shared__ unsigned short Bs[128 * 32];
    const int t = threadIdx.x;
    const int lane = t & 63;
    const int c = lane & 15, qd = lane >> 4;
    const int wave = t >> 6;
    const int wr = (wave >> 1) * 64, wc = (wave & 1) * 64;
    const int bm = blockIdx.x * 128, bn = blockIdx.y * 128;

    f32x4 acc[4][4] = {};

    const unsigned short* Ap = A + (size_t)(bm + (t >> 2)) * K + (t & 3) * 8;
    const unsigned short* Bp = Bt + (size_t)(bn + (t >> 2)) * K + (t & 3) * 8;
    unsigned short* Asw = &As[t * 8];
    unsigned short* Bsw = &Bs[t * 8];

    for (int k0 = 0; k0 < K; k0 += 32) {
        __syncthreads();
        ASYNC16(Ap + k0, Asw);
        ASYNC16(Ap + (size_t)64 * K + k0, Asw + 2048);
        ASYNC16(Bp + k0, Bsw);
        ASYNC16(Bp + (size_t)64 * K + k0, Bsw + 2048);
        __syncthreads();
        bf16x8 af[4], bfr[4];
        for (int i = 0; i < 4; i++)
            af[i] = *(const bf16x8*)&As[(wr + i * 16 + c) * 32 + qd * 8];
        for (int j = 0; j < 4; j++)
            bfr[j] = *(const bf16x8*)&Bs[(wc + j * 16 + c) * 32 + qd * 8];
        for (int i = 0; i < 4; i++)
            for (int j = 0; j < 4; j++)
                acc[i][j] = __builtin_amdgcn_mfma_f32_16x16x32_bf16(af[i], bfr[j], acc[i][j], 0, 0, 0);
    }

    if (MODE == 0) {
        for (int i = 0; i < 4; i++) {
            int row0 = bm + wr + i * 16 + qd * 4;
            for (int j = 0; j < 4; j++) {
                int col = bn + wc + j * 16 + c;
                float bv = bias[col];
                for (int r = 0; r < 4; r++)
                    outf[(size_t)(row0 + r) * N + col] = acc[i][j][r] + bv;
            }
        }
    } else {
        if (bn < 1024) {              // Q, pre-scaled
            for (int i = 0; i < 4; i++) {
                int row0 = bm + wr + i * 16 + qd * 4;
                for (int j = 0; j < 4; j++) {
                    int col = bn + wc + j * 16 + c;
                    float bv = bias[col];
                    for (int r = 0; r < 4; r++)
                        qo[(size_t)(row0 + r) * 1024 + col] = f2b((acc[i][j][r] + bv) * QSCALE);
                }
            }
        } else if (bn < 2048) {       // K
            for (int i = 0; i < 4; i++) {
                int row0 = bm + wr + i * 16 + qd * 4;
                for (int j = 0; j < 4; j++) {
                    int col = bn + wc + j * 16 + c;
                    float bv = bias[col];
                    for (int r = 0; r < 4; r++)
                        ko[(size_t)(row0 + r) * 1024 + (col - 1024)] = f2b(acc[i][j][r] + bv);
                }
            }
        } else {                      // V -> vT16[(b*16+h)*64+d][t]
            int b = bm >> 11;
            int tb = (bm & 2047) + wr;
            for (int i = 0; i < 4; i++) {
                int t0 = tb + i * 16 + qd * 4;
                for (int j = 0; j < 4; j++) {
                    int col = bn + wc + j * 16 + c;
                    float bv = bias[col];
                    int d = col - 2048;
                    int hh = d >> 6, dl = d & 63;
                    ushort4v pk;
                    pk.x = f2b(acc[i][j][0] + bv); pk.y = f2b(acc[i][j][1] + bv);
                    pk.z = f2b(acc[i][j][2] + bv); pk.w = f2b(acc[i][j][3] + bv);
                    *(ushort4v*)&vo[(((size_t)b * 16 + hh) * 64 + dl) * TT + t0] = pk;
                }
            }
        }
    }
}

// ------------- flash attention, S^T form, 32x32x16 MFMA -------------
// 32x32x16 frags: A[m=lane&31][k=(lane>>5)*8+e], B[k=(lane>>5)*8+e][n=lane&31],
// C/D: col=lane&31, row=(reg&3)+8*(reg>>2)+4*(lane>>5)  [m74/m101]
__global__ __launch_bounds__(256, 4) void k_attn(const unsigned short* __restrict__ q16,
                                                 const unsigned short* __restrict__ k16,
                                                 const unsigned short* __restrict__ vT16,
                                                 unsigned short* __restrict__ y16) {
    const int h = blockIdx.y, b = blockIdx.z;
    // balance swizzle: blocks n, n+256, n+512, n+768 land on one CU under
    // stride-256 assignment and share (x,h) but alternate b-parity; the XOR
    // pairs qi with 15-qi so any such quadruple sums to a constant 68 tiles.
    const int qi = (((int)blockIdx.x + h) & 15) ^ ((b & 1) ? 15 : 0);
    __shared__ unsigned short q_s[128 * 72];   // [q][d]
    __shared__ unsigned short k_s[64 * 72];    // [kv][d]
    __shared__ unsigned short vt_s[64 * 72];   // [d][kv]
    const int t = threadIdx.x, lane = t & 63, wave = t >> 6;
    const int l31 = lane & 31, hl = lane >> 5;
    const int wq = wave * 32;

    // stage Q tile 128x64 (already scaled)
    {
        int row = t >> 1, c32 = (t & 1) * 32;
        const unsigned short* src = q16 + ((size_t)(b * TT + qi * 128 + row)) * CC + h * 64 + c32;
        ushort8 v0 = *(const ushort8*)(src);
        ushort8 v1 = *(const ushort8*)(src + 8);
        ushort8 v2 = *(const ushort8*)(src + 16);
        ushort8 v3 = *(const ushort8*)(src + 24);
        *(ushort8*)&q_s[row * 72 + c32] = v0;
        *(ushort8*)&q_s[row * 72 + c32 + 8] = v1;
        *(ushort8*)&q_s[row * 72 + c32 + 16] = v2;
        *(ushort8*)&q_s[row * 72 + c32 + 24] = v3;
    }
    __syncthreads();
    bf16x8 qf[4];
    for (int s = 0; s < 4; s++)
        qf[s] = *(const bf16x8*)&q_s[(wq + l31) * 72 + s * 16 + hl * 8];

    f32x16 oacc[2] = {};
    float m = -3e38f, l = 0.f;
    const int qmaxw = qi * 128 + wq + 31;
    const int qminw = qi * 128 + wq;
    const int qg = qi * 128 + wq + l31;
    const int jn = 2 * qi + 2;
    const unsigned short* kbase = k16 + (size_t)b * TT * CC + h * 64;
    const unsigned short* vbase = vT16 + (((size_t)b * 16 + h) * 64) * TT;

    const int row = t >> 2, c16 = (t & 3) * 16;
    const unsigned short* ksrc = kbase + (size_t)row * CC + c16;
    const unsigned short* vsrc = vbase + (size_t)row * TT + c16;
    ushort8 ka = *(const ushort8*)ksrc, kb = *(const ushort8*)(ksrc + 8);
    ushort8 va = *(const ushort8*)vsrc, vb = *(const ushort8*)(vsrc + 8);

    for (int j = 0; j < jn; j++) {
        __syncthreads();   // all waves done reading prev k_s/vt_s
        *(ushort8*)&k_s[row * 72 + c16] = ka;
        *(ushort8*)&k_s[row * 72 + c16 + 8] = kb;
        *(ushort8*)&vt_s[row * 72 + c16] = va;
        *(ushort8*)&vt_s[row * 72 + c16 + 8] = vb;
        __syncthreads();
        if (j + 1 < jn) {   // prefetch next tile; latency hides behind compute
            const unsigned short* kn = ksrc + (size_t)(j + 1) * 64 * CC;
            const unsigned short* vn = vsrc + (j + 1) * 64;
            ka = *(const ushort8*)kn; kb = *(const ushort8*)(kn + 8);
            va = *(const ushort8*)vn; vb = *(const ushort8*)(vn + 8);
        }
        if (j * 64 > qmaxw) continue;   // fully-masked for this wave (wave-uniform)

        // S^T = K * Q^T
        f32x16 sacc[2] = {};
        for (int c2 = 0; c2 < 2; c2++)
            for (int s = 0; s < 4; s++) {
                bf16x8 kf = *(const bf16x8*)&k_s[(c2 * 32 + l31) * 72 + s * 16 + hl * 8];
                sacc[c2] = __builtin_amdgcn_mfma_f32_32x32x16_bf16(kf, qf[s], sacc[c2], 0, 0, 0);
            }

        if (j * 64 + 63 > qminw) {   // diagonal tile: mask kv > q
            for (int c2 = 0; c2 < 2; c2++)
                for (int r = 0; r < 16; r++) {
                    int kvg = j * 64 + c2 * 32 + (r & 3) + 8 * (r >> 2) + 4 * hl;
                    if (kvg > qg) sacc[c2][r] = -1e30f;
                }
        }

        // online softmax in exp2 domain: p = 2^(s*L - mn*L), 2 insts/prob
        float mx = -1e30f;
        for (int c2 = 0; c2 < 2; c2++)
            for (int r = 0; r < 16; r++) mx = fmaxf(mx, sacc[c2][r]);
        mx = fmaxf(mx, __shfl_xor(mx, 32, 64));
        float mn = fmaxf(m, mx);
        float negmnl = -mn * LOG2E;
        float alpha = fexp2(fmaf(m, LOG2E, negmnl));
        m = mn;
        float sum = 0.f;
        unsigned pg[2][4][2];
        for (int c2 = 0; c2 < 2; c2++)
            for (int g = 0; g < 4; g++) {
                float p0 = fexp2(fmaf(sacc[c2][g * 4 + 0], LOG2E, negmnl));
                float p1 = fexp2(fmaf(sacc[c2][g * 4 + 1], LOG2E, negmnl));
                float p2 = fexp2(fmaf(sacc[c2][g * 4 + 2], LOG2E, negmnl));
                float p3 = fexp2(fmaf(sacc[c2][g * 4 + 3], LOG2E, negmnl));
                sum += (p0 + p1) + (p2 + p3);
                pg[c2][g][0] = pack2(p0, p1);
                pg[c2][g][1] = pack2(p2, p3);
            }
        sum += __shfl_xor(sum, 32, 64);
        l = l * alpha + sum;
        if (__ballot(alpha != 1.0f)) {   // skip rescale once max has stabilized
            for (int c2 = 0; c2 < 2; c2++)
                for (int r = 0; r < 16; r++) oacc[c2][r] *= alpha;
        }

        // C-layout -> B-operand layout: half-swap with partner lane (lane^32)
        bf16x8 pf[4];
        for (int c2 = 0; c2 < 2; c2++)
            for (int pr = 0; pr < 2; pr++) {
                unsigned se0 = hl ? pg[c2][2 * pr][0] : pg[c2][2 * pr + 1][0];
                unsigned se1 = hl ? pg[c2][2 * pr][1] : pg[c2][2 * pr + 1][1];
                unsigned r0 = (unsigned)__shfl_xor((int)se0, 32, 64);
                unsigned r1 = (unsigned)__shfl_xor((int)se1, 32, 64);
                union { unsigned u[4]; bf16x8 v; } fr;
                fr.u[0] = hl ? r0 : pg[c2][2 * pr][0];
                fr.u[1] = hl ? r1 : pg[c2][2 * pr][1];
                fr.u[2] = hl ? pg[c2][2 * pr + 1][0] : r0;
                fr.u[3] = hl ? pg[c2][2 * pr + 1][1] : r1;
                pf[c2 * 2 + pr] = fr.v;
            }

        // O^T += V^T * P^T
        for (int s = 0; s < 4; s++)
            for (int c2o = 0; c2o < 2; c2o++) {
                bf16x8 vf = *(const bf16x8*)&vt_s[(c2o * 32 + l31) * 72 + s * 16 + hl * 8];
                oacc[c2o] = __builtin_amdgcn_mfma_f32_32x32x16_bf16(vf, pf[s], oacc[c2o], 0, 0, 0);
            }
    }

    // epilogue: y[token=qg][h*64 + d]
    float rl = 1.0f / l;
    size_t rowb = ((size_t)b * TT + qg) * CC + h * 64;
    for (int c2 = 0; c2 < 2; c2++)
        for (int g = 0; g < 4; g++) {
            ushort4v pk;
            pk.x = f2b(oacc[c2][g * 4 + 0] * rl);
            pk.y = f2b(oacc[c2][g * 4 + 1] * rl);
            pk.z = f2b(oacc[c2][g * 4 + 2] * rl);
            pk.w = f2b(oacc[c2][g * 4 + 3] * rl);
            *(ushort4v*)&y16[rowb + c2 * 32 + g * 8 + hl * 4] = pk;
        }
}

extern "C" void kernel_launch(void* const* d_in, const int* in_sizes, int n_in,
                              void* d_out, int out_size, void* d_ws, size_t ws_size,
                              hipStream_t stream) {
    const float* x     = (const float*)d_in[0];
    const float* Wqkv  = (const float*)d_in[1];
    const float* bqkv  = (const float*)d_in[2];
    const float* Wproj = (const float*)d_in[3];
    const float* bproj = (const float*)d_in[4];
    float* out = (float*)d_out;

    const int M = BB * TT;   // 8192
    unsigned short* x16    = (unsigned short*)d_ws;          // M*C
    unsigned short* y16    = x16;                            // alias (x dead after GEMM1)
    unsigned short* wqkvT  = x16 + (size_t)M * CC;           // 3C*C
    unsigned short* wprojT = wqkvT + (size_t)3 * CC * CC;    // C*C
    unsigned short* q16    = wprojT + (size_t)CC * CC;       // M*C (scaled)
    unsigned short* k16    = q16 + (size_t)M * CC;           // M*C
    unsigned short* vT16   = k16 + (size_t)M * CC;           // [B*H][64][T] = M*C

    k_cast<<<(M * CC) / 1024, 256, 0, stream>>>(x, x16, M * CC);
    k_transpose_bf16<<<dim3(3 * CC / 32, CC / 32), dim3(32, 8), 0, stream>>>(Wqkv, wqkvT, CC, 3 * CC);
    k_transpose_bf16<<<dim3(CC / 32, CC / 32), dim3(32, 8), 0, stream>>>(Wproj, wprojT, CC, CC);
    k_gemm<1><<<dim3(M / 128, 3 * CC / 128), 256, 0, stream>>>(x16, wqkvT, bqkv, nullptr,
                                                               q16, k16, vT16, M, 3 * CC, CC);
    k_attn<<<dim3(TT / 128, HH, BB), 256, 0, stream>>>(q16, k16, vT16, y16);
    k_gemm<0><<<dim3(M / 128, CC / 128), 256, 0, stream>>>(y16, wprojT, bproj, out,
                                                           nullptr, nullptr, nullptr, M, CC, CC);
}